// Round 1
// baseline (648.715 us; speedup 1.0000x reference)
//
#include <hip/hip_runtime.h>
#include <cstdint>
#include <cstddef>

typedef __bf16 bf16x8v __attribute__((ext_vector_type(8)));
typedef float f32x4v __attribute__((ext_vector_type(4)));

// async global->LDS, 16B per lane; LDS dest must be wave-uniform base (HW adds lane*16)
__device__ __forceinline__ void gload_lds16(const void* g, void* l) {
  __builtin_amdgcn_global_load_lds((const __attribute__((address_space(1))) void*)g,
                                   (__attribute__((address_space(3))) void*)l,
                                   16, 0, 0);
}

__device__ __forceinline__ bf16x8v cvt_bf16x8(f32x4v a, f32x4v b) {
  bf16x8v r;
  r[0] = (__bf16)a[0]; r[1] = (__bf16)a[1]; r[2] = (__bf16)a[2]; r[3] = (__bf16)a[3];
  r[4] = (__bf16)b[0]; r[5] = (__bf16)b[1]; r[6] = (__bf16)b[2]; r[7] = (__bf16)b[3];
  return r;
}

// ---------------- prep: build toep (1024x1024 bf16, [N][K]) and Wcat (128x1024 bf16) ----
__global__ __launch_bounds__(256) void prep_kernel(const float* __restrict__ W1,
                                                   const float* __restrict__ Wslope,
                                                   const float* __restrict__ Wint,
                                                   __bf16* __restrict__ toep,
                                                   __bf16* __restrict__ Wcat) {
  int id = blockIdx.x * 256 + threadIdx.x;
  if (id < 1024 * 1024) {
    int i = id >> 10, j = id & 1023;
    int p = 1023 - i + j;                       // params index
    float v = (p < 1024) ? W1[(size_t)(1023 - p) << 10]   // W1[i-j][0]
                         : W1[p - 1023];                  // W1[0][j-i]
    toep[id] = (__bf16)v;
  } else {
    int id2 = id - 1024 * 1024;                 // < 128*1024
    int n = id2 >> 10, k = id2 & 1023;
    float v = (n < 64) ? Wslope[((size_t)n << 10) + k] : Wint[((size_t)(n - 64) << 10) + k];
    Wcat[id2] = (__bf16)v;
  }
}

// ---------------- GEMM1: q = relu(concat(x,h) @ toep^T + b1), bf16 out ----------------
// tile 128x128, BK=32, 256 thr = 4 waves (2x2 of 64x64), mfma_f32_16x16x32_bf16
__global__ __launch_bounds__(256) void gemm1_kernel(const float* __restrict__ x,
                                                    const float* __restrict__ h,
                                                    const __bf16* __restrict__ toep,
                                                    const float* __restrict__ b1,
                                                    __bf16* __restrict__ q) {
  __shared__ __align__(16) __bf16 At[128 * 32];
  __shared__ __align__(16) __bf16 Bt[128 * 32];
  const int tid = threadIdx.x;
  const int wid = tid >> 6;
  const int lane = tid & 63;
  const int wrow = wid >> 1, wcol = wid & 1;
  const int m0 = (blockIdx.x >> 3) << 7;        // 512 M-tiles
  const int n0 = (blockIdx.x & 7) << 7;         // 8 N-tiles (adjacent bids share M-tile -> LLC reuse of A)
  const int quad = lane >> 4, l15 = lane & 15;
  const int rl = lane >> 2, seg = lane & 3;     // staging: 4 lanes/row, 16 rows/pass

  f32x4v acc[4][4] = {};

  // A source select is block-uniform: k-tiles never straddle the 64-col x/h boundary
  auto a_ptr = [&](int k0, int t) -> const f32x4v* {
    const float* s; int ld, kk;
    if (k0 < 64) { s = x; ld = 64; kk = k0; } else { s = h; ld = 960; kk = k0 - 64; }
    int row = m0 + wid * 32 + t * 16 + rl;
    return (const f32x4v*)(s + (size_t)row * ld + kk + seg * 8);
  };

  f32x4v pv[2][2];
  {
    const f32x4v* p0 = a_ptr(0, 0); pv[0][0] = p0[0]; pv[0][1] = p0[1];
    const f32x4v* p1 = a_ptr(0, 1); pv[1][0] = p1[0]; pv[1][1] = p1[1];
  }

  for (int k0 = 0; k0 < 1024; k0 += 32) {
    __syncthreads();
    // stage B tile [128][32] bf16 via async global->LDS (wave w covers rows w*32..w*32+31)
    {
      int rb = wid * 32;
#pragma unroll
      for (int c = 0; c < 2; ++c) {
        int row = rb + c * 16 + rl;
        const __bf16* g = toep + (((size_t)(n0 + row)) << 10) + k0 + seg * 8;
        gload_lds16(g, &Bt[(rb + c * 16) * 32]);
      }
    }
    // stage A tile from prefetched fp32 regs -> bf16 -> ds_write_b128
#pragma unroll
    for (int t = 0; t < 2; ++t) {
      int row = wid * 32 + t * 16 + rl;
      *(bf16x8v*)&At[row * 32 + seg * 8] = cvt_bf16x8(pv[t][0], pv[t][1]);
    }
    __syncthreads();
    // prefetch next iteration's A (global regs only; overlaps MFMA phase)
    if (k0 + 32 < 1024) {
      const f32x4v* p0 = a_ptr(k0 + 32, 0);
      f32x4v n00 = p0[0], n01 = p0[1];
      const f32x4v* p1 = a_ptr(k0 + 32, 1);
      f32x4v n10 = p1[0], n11 = p1[1];
      pv[0][0] = n00; pv[0][1] = n01; pv[1][0] = n10; pv[1][1] = n11;
    }
    // fragments + MFMA: per wave 8x ds_read_b128, 16 MFMA
    bf16x8v af[4], bfr[4];
#pragma unroll
    for (int r = 0; r < 4; ++r)
      af[r] = *(const bf16x8v*)&At[(wrow * 64 + r * 16 + l15) * 32 + quad * 8];
#pragma unroll
    for (int c = 0; c < 4; ++c)
      bfr[c] = *(const bf16x8v*)&Bt[(wcol * 64 + c * 16 + l15) * 32 + quad * 8];
#pragma unroll
    for (int r = 0; r < 4; ++r)
#pragma unroll
      for (int c = 0; c < 4; ++c)
        acc[r][c] = __builtin_amdgcn_mfma_f32_16x16x32_bf16(af[r], bfr[c], acc[r][c], 0, 0, 0);
  }

  // epilogue: +bias, relu, bf16 store. C/D: col=lane&15, row=quad*4+reg
#pragma unroll
  for (int c = 0; c < 4; ++c) {
    int col = n0 + wcol * 64 + c * 16 + l15;
    float bias = b1[col];
#pragma unroll
    for (int r = 0; r < 4; ++r)
#pragma unroll
      for (int e = 0; e < 4; ++e) {
        int row = m0 + wrow * 64 + r * 16 + quad * 4 + e;
        float v = fmaxf(acc[r][c][e] + bias, 0.0f);
        q[((size_t)row << 10) + col] = (__bf16)v;
      }
  }
}

// ---------------- GEMM2: [slope|intercept] = act(q @ Wcat^T + bias) -------------------
// tile 128 rows x full N=128, BK=32
__global__ __launch_bounds__(256) void gemm2_kernel(const __bf16* __restrict__ q,
                                                    const __bf16* __restrict__ Wcat,
                                                    const float* __restrict__ b_slope,
                                                    const float* __restrict__ b_int,
                                                    float* __restrict__ out) {
  __shared__ __align__(16) __bf16 At[128 * 32];
  __shared__ __align__(16) __bf16 Bt[128 * 32];
  const int tid = threadIdx.x;
  const int wid = tid >> 6, lane = tid & 63;
  const int wrow = wid >> 1, wcol = wid & 1;
  const int m0 = blockIdx.x << 7;
  const int quad = lane >> 4, l15 = lane & 15;
  const int rl = lane >> 2, seg = lane & 3;

  f32x4v acc[4][4] = {};

  for (int k0 = 0; k0 < 1024; k0 += 32) {
    __syncthreads();
#pragma unroll
    for (int c = 0; c < 2; ++c) {
      int row = wid * 32 + c * 16 + rl;
      gload_lds16(q + (((size_t)(m0 + row)) << 10) + k0 + seg * 8, &At[(wid * 32 + c * 16) * 32]);
      gload_lds16(Wcat + (((size_t)row) << 10) + k0 + seg * 8, &Bt[(wid * 32 + c * 16) * 32]);
    }
    __syncthreads();
    bf16x8v af[4], bfr[4];
#pragma unroll
    for (int r = 0; r < 4; ++r)
      af[r] = *(const bf16x8v*)&At[(wrow * 64 + r * 16 + l15) * 32 + quad * 8];
#pragma unroll
    for (int c = 0; c < 4; ++c)
      bfr[c] = *(const bf16x8v*)&Bt[(wcol * 64 + c * 16 + l15) * 32 + quad * 8];
#pragma unroll
    for (int r = 0; r < 4; ++r)
#pragma unroll
      for (int c = 0; c < 4; ++c)
        acc[r][c] = __builtin_amdgcn_mfma_f32_16x16x32_bf16(af[r], bfr[c], acc[r][c], 0, 0, 0);
  }

#pragma unroll
  for (int c = 0; c < 4; ++c) {
    int col = wcol * 64 + c * 16 + l15;         // 0..127; col<64 is wave-uniform (wcol)
    float bias = (col < 64) ? b_slope[col] : b_int[col - 64];
#pragma unroll
    for (int r = 0; r < 4; ++r)
#pragma unroll
      for (int e = 0; e < 4; ++e) {
        int row = m0 + wrow * 64 + r * 16 + quad * 4 + e;
        float v = acc[r][c][e] + bias;
        if (col < 64) {
          float xc = fminf(fmaxf(v, -15.f), 15.f);
          float t = __expf(2.f * xc);
          out[(size_t)row * 64 + col] = (t - 1.f) / (t + 1.f);   // tanh
        } else {
          out[(size_t)4194304 + (size_t)row * 64 + (col - 64)] = v;
        }
      }
  }
}

extern "C" void kernel_launch(void* const* d_in, const int* in_sizes, int n_in,
                              void* d_out, int out_size, void* d_ws, size_t ws_size,
                              hipStream_t stream) {
  const float* x  = (const float*)d_in[0];   // [65536,64]
  const float* h  = (const float*)d_in[1];   // [65536,960]
  const float* W1 = (const float*)d_in[2];   // [1024,1024]
  const float* b1 = (const float*)d_in[3];   // [1024]
  const float* Ws = (const float*)d_in[4];   // [64,1024]
  const float* bs = (const float*)d_in[5];   // [64]
  const float* Wi = (const float*)d_in[6];   // [64,1024]
  const float* bi = (const float*)d_in[7];   // [64]
  char* ws = (char*)d_ws;
  // ws layout: q bf16 [65536,1024] (134217728 B) | toep bf16 [1024,1024] (2 MiB) | Wcat bf16 [128,1024]
  __bf16* q    = (__bf16*)ws;
  __bf16* toep = (__bf16*)(ws + (size_t)134217728);
  __bf16* Wcat = (__bf16*)(ws + (size_t)134217728 + (size_t)2097152);

  hipLaunchKernelGGL(prep_kernel,  dim3(4608), dim3(256), 0, stream, W1, Ws, Wi, toep, Wcat);
  hipLaunchKernelGGL(gemm1_kernel, dim3(4096), dim3(256), 0, stream, x, h, toep, b1, q);
  hipLaunchKernelGGL(gemm2_kernel, dim3(512),  dim3(256), 0, stream, q, Wcat, bs, bi, (float*)d_out);
}